// Round 7
// baseline (279.524 us; speedup 1.0000x reference)
//
#include <hip/hip_runtime.h>
#include <hip/hip_bf16.h>
#include <math.h>

#define DIM 128
#define NHEAD 8
#define DHEAD 16
#define HID 512
#define LN_EPS 1e-5f
// (1/sqrt(128))*log2(e) folded into q so softmax runs in exp2 domain
#define QSCALE 0.12751879104863297f

typedef __bf16 bf16x8 __attribute__((ext_vector_type(8)));
typedef float f32x4 __attribute__((ext_vector_type(4)));
typedef float f32x2 __attribute__((ext_vector_type(2)));
typedef _Float16 f16x2 __attribute__((ext_vector_type(2)));

__device__ inline float bf2f(unsigned int bits16) {
    return __uint_as_float(bits16 << 16);
}
__device__ inline unsigned short f2bf(float f) {
    unsigned int u = __float_as_uint(f);
    unsigned int r = u + 0x7fff + ((u >> 16) & 1);   // RNE
    return (unsigned short)(r >> 16);
}
__device__ inline unsigned short f2h(float f) {
    _Float16 h = (_Float16)f;
    return __builtin_bit_cast(unsigned short, h);
}
__device__ inline float h2f(unsigned short h) {
    return (float)__builtin_bit_cast(_Float16, h);
}
// pack two floats -> two OCP e4m3 bytes (low ushort)
__device__ inline unsigned short pk_fp8(float a, float b) {
    int r = __builtin_amdgcn_cvt_pk_fp8_f32(a, b, 0, false);
    return (unsigned short)(r & 0xffff);
}
// unpack 2 fp8 bytes from low/high halfword
__device__ inline f32x2 unpk_fp8_lo(unsigned int w) {
    return __builtin_amdgcn_cvt_pk_f32_fp8((int)w, false);
}
__device__ inline f32x2 unpk_fp8_hi(unsigned int w) {
    return __builtin_amdgcn_cvt_pk_f32_fp8((int)w, true);
}
__device__ inline float fexp2(float x) { return __builtin_amdgcn_exp2f(x); }

// dot of 16 fp8 values (one uint4) against 16 floats, fully in-lane
__device__ __forceinline__ float dot16_fp8(uint4 w, const float (&q)[16]) {
    f32x2 a0 = unpk_fp8_lo(w.x), b0 = unpk_fp8_hi(w.x);
    f32x2 a1 = unpk_fp8_lo(w.y), b1 = unpk_fp8_hi(w.y);
    f32x2 a2 = unpk_fp8_lo(w.z), b2 = unpk_fp8_hi(w.z);
    f32x2 a3 = unpk_fp8_lo(w.w), b3 = unpk_fp8_hi(w.w);
    float t0 = fmaf(a0.x, q[0],  fmaf(a0.y, q[1],  fmaf(b0.x, q[2],  b0.y * q[3])));
    float t1 = fmaf(a1.x, q[4],  fmaf(a1.y, q[5],  fmaf(b1.x, q[6],  b1.y * q[7])));
    float t2 = fmaf(a2.x, q[8],  fmaf(a2.y, q[9],  fmaf(b2.x, q[10], b2.y * q[11])));
    float t3 = fmaf(a3.x, q[12], fmaf(a3.y, q[13], fmaf(b3.x, q[14], b3.y * q[15])));
    return (t0 + t1) + (t2 + t3);
}

// acc[j] += v_j * wt for 16 fp8 values (one uint4), fully in-lane
__device__ __forceinline__ void pv16_fp8(uint4 w, float wt, float (&acc)[16]) {
    f32x2 a0 = unpk_fp8_lo(w.x), b0 = unpk_fp8_hi(w.x);
    f32x2 a1 = unpk_fp8_lo(w.y), b1 = unpk_fp8_hi(w.y);
    f32x2 a2 = unpk_fp8_lo(w.z), b2 = unpk_fp8_hi(w.z);
    f32x2 a3 = unpk_fp8_lo(w.w), b3 = unpk_fp8_hi(w.w);
    acc[0]  = fmaf(a0.x, wt, acc[0]);  acc[1]  = fmaf(a0.y, wt, acc[1]);
    acc[2]  = fmaf(b0.x, wt, acc[2]);  acc[3]  = fmaf(b0.y, wt, acc[3]);
    acc[4]  = fmaf(a1.x, wt, acc[4]);  acc[5]  = fmaf(a1.y, wt, acc[5]);
    acc[6]  = fmaf(b1.x, wt, acc[6]);  acc[7]  = fmaf(b1.y, wt, acc[7]);
    acc[8]  = fmaf(a2.x, wt, acc[8]);  acc[9]  = fmaf(a2.y, wt, acc[9]);
    acc[10] = fmaf(b2.x, wt, acc[10]); acc[11] = fmaf(b2.y, wt, acc[11]);
    acc[12] = fmaf(a3.x, wt, acc[12]); acc[13] = fmaf(a3.y, wt, acc[13]);
    acc[14] = fmaf(b3.x, wt, acc[14]); acc[15] = fmaf(b3.y, wt, acc[15]);
}

// ---------------- k1: prep (feat->bf16, weight transposes) + count atomics + ranks ----------------
// counts zeroed by hipMemsetAsync before this kernel.
// blocks: [0,fb) featb | [fb,fb+192) Wqkv | +256 W1t | +256 W2t | [wb, wb+cb) count+rank
__global__ __launch_bounds__(256) void prep_count_kernel(
        int* counts, int* __restrict__ ranks, int Nn,
        const float* __restrict__ feat, unsigned short* __restrict__ featb,
        const float* __restrict__ Wq, const float* __restrict__ Wk, const float* __restrict__ Wv,
        unsigned short* __restrict__ Wqkvt,
        const float* __restrict__ W1, unsigned short* __restrict__ W1t,
        const float* __restrict__ W2, unsigned short* __restrict__ W2t,
        const int* __restrict__ dst, int E, int fb, int wb) {
    int blk = blockIdx.x, t = threadIdx.x;
    if (blk < fb) {
        int i = blk * 256 + t;            // quad index
        if (i < Nn * 32) {
            float4 v = *(const float4*)(feat + (size_t)i * 4);
            ushort4 o;
            o.x = f2bf(v.x); o.y = f2bf(v.y); o.z = f2bf(v.z); o.w = f2bf(v.w);
            *(ushort4*)(featb + (size_t)i * 4) = o;
        }
    } else if (blk < wb) {
        int b2_ = blk - fb;
        if (b2_ < 192) {
            int sec = b2_ >> 6;
            const float* W = sec == 0 ? Wq : (sec == 1 ? Wk : Wv);
            int o = (b2_ & 63) * 256 + t;
            int oc = o >> 7, orow = o & 127;
            Wqkvt[sec * 16384 + o] = f2bf(W[(size_t)orow * 128 + oc]);
        } else if (b2_ < 448) {
            int o = (b2_ - 192) * 256 + t;
            int oc = o >> 7, orow = o & 127;
            W1t[o] = f2bf(W1[(size_t)orow * 512 + oc]);
        } else {
            int o = (b2_ - 448) * 256 + t;
            int oc = o >> 9, orow = o & 511;
            W2t[o] = f2bf(W2[(size_t)orow * 128 + oc]);
        }
    } else {
        int e0 = (blk - wb) * 1024 + t * 4;
        if (e0 + 3 < E) {
            int4 d = *(const int4*)(dst + e0);
            int4 r;
            r.x = atomicAdd(&counts[d.x], 1);
            r.y = atomicAdd(&counts[d.y], 1);
            r.z = atomicAdd(&counts[d.z], 1);
            r.w = atomicAdd(&counts[d.w], 1);
            *(int4*)(ranks + e0) = r;
        } else {
            for (int e = e0; e < E; ++e) ranks[e] = atomicAdd(&counts[dst[e]], 1);
        }
    }
}

// ---------------- scan ----------------

__global__ __launch_bounds__(256) void scanA_kernel(const int* __restrict__ counts, int* bsum, int Nn) {
    int blk = blockIdx.x, t = threadIdx.x;
    int i = blk * 1024 + t * 4;
    int s = 0;
    if (i < Nn) { int4 x = *(const int4*)(counts + i); s = x.x + x.y + x.z + x.w; }
#pragma unroll
    for (int off = 1; off < 64; off <<= 1) s += __shfl_xor(s, off, 64);
    __shared__ int wt[4];
    if ((t & 63) == 0) wt[t >> 6] = s;
    __syncthreads();
    if (t == 0) bsum[blk] = wt[0] + wt[1] + wt[2] + wt[3];
}

__global__ __launch_bounds__(256) void scanC_kernel(const int* __restrict__ counts, const int* __restrict__ bsum,
                                                    int* offsets, int Nn, int NCH) {
    int blk = blockIdx.x, t = threadIdx.x, lane = t & 63, wv = t >> 6;
    __shared__ int wt[4];
    __shared__ int base_s;
    if (wv == 0) {
        int v = (lane < NCH) ? bsum[lane] : 0;
        int s = v;
#pragma unroll
        for (int off = 1; off < 64; off <<= 1) {
            int u = __shfl_up(s, off, 64);
            if (lane >= off) s += u;
        }
        int basev = (blk > 0) ? __shfl(s, blk - 1, 64) : 0;
        int tot = __shfl(s, NCH - 1, 64);
        if (lane == 0) {
            base_s = basev;
            if (blk == 0) offsets[Nn] = tot;
        }
    }
    int i = blk * 1024 + t * 4;
    int4 x = make_int4(0, 0, 0, 0);
    if (i < Nn) x = *(const int4*)(counts + i);
    int ts = x.x + x.y + x.z + x.w;
    int s = ts;
#pragma unroll
    for (int off = 1; off < 64; off <<= 1) {
        int u = __shfl_up(s, off, 64);
        if (lane >= off) s += u;
    }
    if (lane == 63) wt[wv] = s;
    __syncthreads();
    int woff = 0;
    for (int wi = 0; wi < wv; ++wi) woff += wt[wi];
    int excl = base_s + woff + (s - ts);
    if (i < Nn) {
        int o0 = excl, o1 = o0 + x.x, o2 = o1 + x.y, o3 = o2 + x.z;
        *(int4*)(offsets + i) = make_int4(o0, o1, o2, o3);
    }
}

// ---------------- k4: fill (CSR scatter, no atomics) + qkv GEMM ----------------
// blocks [0, cb): fill; blocks [cb, cb+MP/64): one 64-row m-tile computing q, k AND v.
// Direct-fragment GEMM: A (featb) fragments loaded ONCE into 64 VGPRs (16 indep 16B
// loads, MLP-hidden), B fragments direct from L2-hot Wqkvt. Zero K-loop barriers;
// LDS (17.4KB) only for the transpose epilogue. A HBM traffic 3x -> 1x.
#define QST 136
__global__ __launch_bounds__(256) void fill_qkv_kernel(
        const int* __restrict__ dst, const int* __restrict__ src,
        const int* __restrict__ ranks, const int* __restrict__ offsets,
        int* __restrict__ srcs, int E, int cb,
        const unsigned short* __restrict__ A, const unsigned short* __restrict__ Bt,
        unsigned short* __restrict__ qb, unsigned char* __restrict__ kv8) {
    int blk = blockIdx.x, t = threadIdx.x;
    if (blk < cb) {
        int e0 = blk * 1024 + t * 4;
        if (e0 + 3 < E) {
            int4 d = *(const int4*)(dst + e0);
            int4 sv = *(const int4*)(src + e0);
            int4 rk = *(const int4*)(ranks + e0);
            srcs[offsets[d.x] + rk.x] = sv.x;
            srcs[offsets[d.y] + rk.y] = sv.y;
            srcs[offsets[d.z] + rk.z] = sv.z;
            srcs[offsets[d.w] + rk.w] = sv.w;
        } else {
            for (int e = e0; e < E; ++e) srcs[offsets[dst[e]] + ranks[e]] = src[e];
        }
        return;
    }
    __shared__ unsigned short smem[64 * QST];
    int m0 = (blk - cb) * 64;
    int wave = t >> 6, lane = t & 63;
    int lrow = lane & 15, kq = lane >> 4;

    // A fragments, persistent: af[kb][mi] = A[m0+mi*16+lrow][kb*32+kq*8 .. +8]
    bf16x8 af[4][4];
    {
        const unsigned short* arow = A + (size_t)(m0 + lrow) * 128 + kq * 8;
#pragma unroll
        for (int kb = 0; kb < 4; ++kb)
#pragma unroll
            for (int mi = 0; mi < 4; ++mi)
                af[kb][mi] = *(const bf16x8*)(arow + mi * 2048 + kb * 32);
    }

    for (int region = 0; region < 3; ++region) {
        const unsigned short* brow =
            Bt + (size_t)region * 16384 + (size_t)(wave * 32 + lrow) * 128 + kq * 8;
        f32x4 acc[4][2] = {};
#pragma unroll
        for (int kb = 0; kb < 4; ++kb) {
            bf16x8 bfr[2];
#pragma unroll
            for (int ni = 0; ni < 2; ++ni)
                bfr[ni] = *(const bf16x8*)(brow + ni * 2048 + kb * 32);
#pragma unroll
            for (int mi = 0; mi < 4; ++mi)
#pragma unroll
                for (int ni = 0; ni < 2; ++ni)
                    acc[mi][ni] = __builtin_amdgcn_mfma_f32_16x16x32_bf16(af[kb][mi], bfr[ni], acc[mi][ni], 0, 0, 0);
        }

        float scale = (region == 0) ? QSCALE : 1.f;
        if (region) __syncthreads();     // prev epilogue readers done before overwrite
#pragma unroll
        for (int ni = 0; ni < 2; ++ni) {
            int col = wave * 32 + ni * 16 + lrow;
#pragma unroll
            for (int mi = 0; mi < 4; ++mi) {
#pragma unroll
                for (int r = 0; r < 4; ++r) {
                    int row = mi * 16 + kq * 4 + r;
                    smem[row * QST + col] = f2h(acc[mi][ni][r] * scale);
                }
            }
        }
        __syncthreads();
        if (region == 0) {
            unsigned short* outp = qb + (size_t)m0 * 128;
#pragma unroll
            for (int i = 0; i < 4; ++i) {
                int chunk = i * 256 + t;         // 0..1023
                int row = chunk >> 4, c16 = chunk & 15;
                *(float4*)(outp + (size_t)chunk * 8) = *(const float4*)(smem + row * QST + c16 * 8);
            }
        } else {
            // fp8 convert + coalesced 16B stores: 64 rows x 8 chunks of 16 dims
            int half = region - 1;   // 0:k, 1:v
#pragma unroll
            for (int i = 0; i < 2; ++i) {
                int chunk = i * 256 + t;         // 0..511
                int row = chunk >> 3, seg = chunk & 7;
                const unsigned short* sp = smem + row * QST + seg * 16;
                unsigned int ow[4];
#pragma unroll
                for (int j = 0; j < 4; ++j) {
                    unsigned int lo = pk_fp8(h2f(sp[4 * j]), h2f(sp[4 * j + 1]));
                    unsigned int hi = pk_fp8(h2f(sp[4 * j + 2]), h2f(sp[4 * j + 3]));
                    ow[j] = lo | (hi << 16);
                }
                *(uint4*)(kv8 + (size_t)(m0 + row) * 256 + half * 128 + seg * 16) =
                    make_uint4(ow[0], ow[1], ow[2], ow[3]);
            }
        }
    }
}

// ---------------- k5: fused attention aggregate + residual + LN1 ----------------
// one wave per node; lane = (edge_slot e = lane>>3, head h = lane&7).
__global__ __launch_bounds__(256) void agg_ln1_kernel(
        const unsigned short* __restrict__ qb, const unsigned char* __restrict__ kv8,
        const float* __restrict__ feat,
        const int* __restrict__ srcs, const int* __restrict__ offsets,
        const float* __restrict__ g, const float* __restrict__ b,
        unsigned short* __restrict__ rstb, int n) {
    int node = blockIdx.x * 4 + (threadIdx.x >> 6);
    int lane = threadIdx.x & 63;
    if (node >= n) return;
    int el = lane >> 3;      // edge slot 0..7
    int h  = lane & 7;       // head 0..7

    // q for this head: 16 f16 (pre-scaled by QSCALE*log2e) -> 16 floats
    const uint4* qp = (const uint4*)(qb + (size_t)node * 128 + h * 16);
    uint4 qlo = qp[0], qhi = qp[1];
    float qf[16];
    {
        unsigned int qw[8] = {qlo.x, qlo.y, qlo.z, qlo.w, qhi.x, qhi.y, qhi.z, qhi.w};
#pragma unroll
        for (int j = 0; j < 8; ++j) {
            f16x2 p2 = __builtin_bit_cast(f16x2, qw[j]);
            qf[2 * j]     = (float)p2.x;
            qf[2 * j + 1] = (float)p2.y;
        }
    }

    int beg = offsets[node], end = offsets[node + 1];
    float l = 0.f;
    float acc[16];
#pragma unroll
    for (int j = 0; j < 16; ++j) acc[j] = 0.f;

    // 16 edges per iteration: 2 slots per lane, all loads issued up front
    for (int idx = beg; idx < end; idx += 16) {
        int e0i = idx + el, e1i = idx + 8 + el;
        bool v0 = e0i < end, v1 = e1i < end;
        int s0 = srcs[v0 ? e0i : beg];
        int s1 = srcs[v1 ? e1i : beg];
        const uint4* kp0 = (const uint4*)(kv8 + (size_t)s0 * 256 + h * 16);
        const uint4* kp1 = (const uint4*)(kv8 + (size_t)s1 * 256 + h * 16);
        uint4 kw0 = kp0[0];
        uint4 vw0 = kp0[8];     // +128B
        uint4 kw1 = kp1[0];
        uint4 vw1 = kp1[8];

        float p0 = dot16_fp8(kw0, qf);
        float p1 = dot16_fp8(kw1, qf);
        float sc0 = v0 ? fminf(fmaxf(p0, -30.f), 30.f) : -1000.f;
        float sc1 = v1 ? fminf(fmaxf(p1, -30.f), 30.f) : -1000.f;
        float w0 = fexp2(sc0);
        float w1 = fexp2(sc1);
        l += w0 + w1;
        pv16_fp8(vw0, w0, acc);
        pv16_fp8(vw1, w1, acc);
    }

    // all-reduce softmax denom across the 8 edge-lanes (lane bits 3,4,5)
    l += __shfl_xor(l, 8, 64);
    l += __shfl_xor(l, 16, 64);
    l += __shfl_xor(l, 32, 64);

    // reduce-scatter acc over edge-lanes: each round halves dims, selects by e-bit
    float r8[8];
    {
        bool b0 = (el & 1) != 0;
#pragma unroll
        for (int j = 0; j < 8; ++j) {
            float send = b0 ? acc[j] : acc[j + 8];
            float keep = b0 ? acc[j + 8] : acc[j];
            r8[j] = keep + __shfl_xor(send, 8, 64);
        }
    }
    float r4[4];
    {
        bool b1 = (el & 2) != 0;
#pragma unroll
        for (int j = 0; j < 4; ++j) {
            float send = b1 ? r8[j] : r8[j + 4];
            float keep = b1 ? r8[j + 4] : r8[j];
            r4[j] = keep + __shfl_xor(send, 16, 64);
        }
    }
    float r2[2];
    {
        bool b2 = (el & 4) != 0;
#pragma unroll
        for (int j = 0; j < 2; ++j) {
            float send = b2 ? r4[j] : r4[j + 2];
            float keep = b2 ? r4[j + 2] : r4[j];
            r2[j] = keep + __shfl_xor(send, 32, 64);
        }
    }
    // lane now owns dims d0, d0+1 with d0 = h*16 + 8*e0 + 4*e1 + 2*e2
    int off = ((el & 1) << 3) | ((el & 2) << 1) | ((el & 4) >> 1);
    int d0 = h * 16 + off;

    float inv = (l > 0.f) ? 1.f / l : 0.f;
    float2 fv = *(const float2*)(feat + (size_t)node * DIM + d0);
    float x0 = r2[0] * inv + fv.x;
    float x1 = r2[1] * inv + fv.y;

    float s1 = x0 + x1;
    float s2 = x0 * x0 + x1 * x1;
#pragma unroll
    for (int off2 = 1; off2 < 64; off2 <<= 1) {
        s1 += __shfl_xor(s1, off2, 64);
        s2 += __shfl_xor(s2, off2, 64);
    }
    float mean = s1 * (1.f / DIM);
    float var = s2 * (1.f / DIM) - mean * mean;
    float rinv = rsqrtf(var + LN_EPS);
    float2 gv = *(const float2*)(g + d0);
    float2 bv = *(const float2*)(b + d0);
    float o0 = (x0 - mean) * rinv * gv.x + bv.x;
    float o1 = (x1 - mean) * rinv * gv.y + bv.y;
    unsigned int packed = (unsigned int)f2bf(o0) | ((unsigned int)f2bf(o1) << 16);
    ((unsigned int*)rstb)[(size_t)node * 64 + (d0 >> 1)] = packed;
}

// ---------------- k6: FFN1: hid = PReLU(rst @ W1 + b1), bf16 out ----------------
// Direct-fragment GEMM: one block per 64-row strip computes ALL 4 hid-chunks;
// A (rstb) fragments loaded ONCE (rstb traffic 4x -> 1x), W1t fragments L2-hot.
__global__ __launch_bounds__(256) void ffn1_gemm(
        const unsigned short* __restrict__ A, const unsigned short* __restrict__ Bt,
        unsigned short* __restrict__ hid,
        const float* __restrict__ b1, const float* __restrict__ prelu) {
    __shared__ unsigned short smem[64 * QST];
    int t = threadIdx.x;
    int wave = t >> 6, lane = t & 63;
    int lrow = lane & 15, kq = lane >> 4;
    int m0 = blockIdx.x * 64;

    bf16x8 af[4][4];
    {
        const unsigned short* arow = A + (size_t)(m0 + lrow) * 128 + kq * 8;
#pragma unroll
        for (int kb = 0; kb < 4; ++kb)
#pragma unroll
            for (int mi = 0; mi < 4; ++mi)
                af[kb][mi] = *(const bf16x8*)(arow + mi * 2048 + kb * 32);
    }

    for (int n0 = 0; n0 < 4; ++n0) {
        const unsigned short* brow =
            Bt + (size_t)(n0 * 128 + wave * 32 + lrow) * 128 + kq * 8;
        f32x4 acc[4][2] = {};
#pragma unroll
        for (int kb = 0; kb < 4; ++kb) {
            bf16x8 bfr[2];
#pragma unroll
            for (int ni = 0; ni < 2; ++ni)
                bfr[ni] = *(const bf16x8*)(brow + ni * 2048 + kb * 32);
#pragma unroll
            for (int mi = 0; mi < 4; ++mi)
#pragma unroll
                for (int ni = 0; ni < 2; ++ni)
                    acc[mi][ni] = __builtin_amdgcn_mfma_f32_16x16x32_bf16(af[kb][mi], bfr[ni], acc[mi][ni], 0, 0, 0);
        }

        if (n0) __syncthreads();
#pragma unroll
        for (int ni = 0; ni < 2; ++ni) {
            int col = wave * 32 + ni * 16 + lrow;
            int cg = n0 * 128 + col;
            float biv = b1[cg], pwv = prelu[cg];
#pragma unroll
            for (int mi = 0; mi < 4; ++mi) {
#pragma unroll
                for (int r = 0; r < 4; ++r) {
                    int row = mi * 16 + kq * 4 + r;
                    float v = acc[mi][ni][r] + biv;
                    v = v >= 0.f ? v : pwv * v;
                    smem[row * QST + col] = f2bf(v);
                }
            }
        }
        __syncthreads();
#pragma unroll
        for (int i = 0; i < 4; ++i) {
            int chunk = i * 256 + t;             // 0..1023
            int row = chunk >> 4, c16 = chunk & 15;
            *(float4*)(hid + (size_t)(m0 + row) * 512 + n0 * 128 + c16 * 8) =
                *(const float4*)(smem + row * QST + c16 * 8);
        }
    }
}

// ---------------- k7: FFN2 + residual + LN2 ----------------
// Direct-fragment K-loop (no LDS staging, no K-loop barriers): hid read once,
// W2t L2-hot. grid (MP/64); wave w owns cols [w*32, w*32+32); two-phase LN reduction.
__global__ __launch_bounds__(256) void ffn2_ln2_kernel(
        const unsigned short* __restrict__ hid, const unsigned short* __restrict__ W2t,
        const unsigned short* __restrict__ rstb,
        const float* __restrict__ b2, const float* __restrict__ g, const float* __restrict__ bb,
        float* __restrict__ out, int Nn) {
    __shared__ float redS[64][4];
    __shared__ float redQ[64][4];
    int t = threadIdx.x;
    int wave = t >> 6, lane = t & 63;
    int lrow = lane & 15, kq = lane >> 4;
    int m0 = blockIdx.x * 64;

    f32x4 acc[4][2] = {};
    {
        const unsigned short* ar = hid + (size_t)(m0 + lrow) * 512 + kq * 8;
        const unsigned short* br = W2t + (size_t)(wave * 32 + lrow) * 512 + kq * 8;
#pragma unroll
        for (int kb = 0; kb < 16; ++kb) {
            bf16x8 af[4], bfr[2];
#pragma unroll
            for (int mi = 0; mi < 4; ++mi)
                af[mi] = *(const bf16x8*)(ar + mi * 8192 + kb * 32);
#pragma unroll
            for (int ni = 0; ni < 2; ++ni)
                bfr[ni] = *(const bf16x8*)(br + ni * 8192 + kb * 32);
#pragma unroll
            for (int mi = 0; mi < 4; ++mi)
#pragma unroll
                for (int ni = 0; ni < 2; ++ni)
                    acc[mi][ni] = __builtin_amdgcn_mfma_f32_16x16x32_bf16(af[mi], bfr[ni], acc[mi][ni], 0, 0, 0);
        }
    }

    float b2v[2], gv[2], bv[2];
    int cols[2];
#pragma unroll
    for (int ni = 0; ni < 2; ++ni) {
        cols[ni] = wave * 32 + ni * 16 + lrow;
        b2v[ni] = b2[cols[ni]]; gv[ni] = g[cols[ni]]; bv[ni] = bb[cols[ni]];
    }
#pragma unroll
    for (int mi = 0; mi < 4; ++mi) {
#pragma unroll
        for (int r = 0; r < 4; ++r) {
            int rloc = mi * 16 + kq * 4 + r;
            int row = m0 + rloc;
            float ps = 0.f, pq = 0.f;
#pragma unroll
            for (int ni = 0; ni < 2; ++ni) {
                float rsv = bf2f(rstb[(size_t)row * 128 + cols[ni]]);
                float v = acc[mi][ni][r] + b2v[ni] + rsv;
                acc[mi][ni][r] = v;
                ps += v; pq += v * v;
            }
#pragma unroll
            for (int off = 1; off < 16; off <<= 1) {
                ps += __shfl_xor(ps, off, 16);
                pq += __shfl_xor(pq, off, 16);
            }
            if (lrow == 0) { redS[rloc][wave] = ps; redQ[rloc][wave] = pq; }
        }
    }
    __syncthreads();
#pragma unroll
    for (int mi = 0; mi < 4; ++mi) {
#pragma unroll
        for (int r = 0; r < 4; ++r) {
            int rloc = mi * 16 + kq * 4 + r;
            int row = m0 + rloc;
            float s1 = redS[rloc][0] + redS[rloc][1] + redS[rloc][2] + redS[rloc][3];
            float sq = redQ[rloc][0] + redQ[rloc][1] + redQ[rloc][2] + redQ[rloc][3];
            float mean = s1 * (1.f / DIM);
            float var = sq * (1.f / DIM) - mean * mean;
            float rs = rsqrtf(var + LN_EPS);
            if (row < Nn) {
#pragma unroll
                for (int ni = 0; ni < 2; ++ni)
                    out[(size_t)row * 128 + cols[ni]] =
                        (acc[mi][ni][r] - mean) * rs * gv[ni] + bv[ni];
            }
        }
    }
}

// ---------------- launch ----------------

extern "C" void kernel_launch(void* const* d_in, const int* in_sizes, int n_in,
                              void* d_out, int out_size, void* d_ws, size_t ws_size,
                              hipStream_t stream) {
    const float* feat   = (const float*)d_in[0];
    const int*   src    = (const int*)d_in[1];
    const int*   dst    = (const int*)d_in[2];
    const float* Wq     = (const float*)d_in[3];
    const float* Wk     = (const float*)d_in[4];
    const float* Wv     = (const float*)d_in[5];
    const float* ln1_g  = (const float*)d_in[6];
    const float* ln1_b  = (const float*)d_in[7];
    const float* ln2_g  = (const float*)d_in[8];
    const float* ln2_b  = (const float*)d_in[9];
    const float* W1     = (const float*)d_in[10];
    const float* b1     = (const float*)d_in[11];
    const float* prelu  = (const float*)d_in[12];
    const float* W2     = (const float*)d_in[13];
    const float* b2     = (const float*)d_in[14];
    float* out = (float*)d_out;

    const int Nn = in_sizes[0] / DIM;        // 40000
    const int E  = in_sizes[1];              // 640000
    const int MP = (Nn + 127) & ~127;        // 40064

    char* w = (char*)d_ws;
    unsigned short* qb   = (unsigned short*)w; w += (size_t)MP * DIM * 2;
    unsigned char*  kv8  = (unsigned char*)w;  w += (size_t)MP * 256;   // 128B k | 128B v per node
    unsigned short* rstb = (unsigned short*)w; w += (size_t)MP * DIM * 2;
    unsigned short* featb= (unsigned short*)w; w += (size_t)MP * DIM * 2;
    unsigned short* hid  = (unsigned short*)w; w += (size_t)MP * HID * 2;
    unsigned short* Wqkvt= (unsigned short*)w; w += 3 * DIM * DIM * 2;
    unsigned short* W1t  = (unsigned short*)w; w += (size_t)HID * DIM * 2;
    unsigned short* W2t  = (unsigned short*)w; w += (size_t)DIM * HID * 2;
    int* counts  = (int*)w;  w += (size_t)Nn * 4;
    int* offsets = (int*)w;  w += (size_t)(Nn + 4) * 4;
    int* bsum    = (int*)w;  w += 64 * 4;
    int* srcs    = (int*)w;
    // ranks aliases hid: hid written by ffn1 only AFTER fill_qkv consumed ranks
    int* ranks   = (int*)hid;

    const int NCH = (Nn + 1023) / 1024;      // 40 (<= 64)
    const int FB  = Nn / 8;                  // featb blocks (Nn*32 quads / 256)
    const int WB  = FB + 704;                // + weight transpose blocks
    const int CB  = (E + 1023) / 1024;       // count/fill blocks

    hipMemsetAsync(counts, 0, (size_t)Nn * 4, stream);
    // hygiene: zero padding rows [Nn, MP) of featb and rstb (read as GEMM A-fragments
    // by padding tiles; were previously uninitialized)
    if (MP > Nn) {
        hipMemsetAsync(featb + (size_t)Nn * DIM, 0, (size_t)(MP - Nn) * DIM * 2, stream);
        hipMemsetAsync(rstb + (size_t)Nn * DIM, 0, (size_t)(MP - Nn) * DIM * 2, stream);
    }

    prep_count_kernel<<<WB + CB, 256, 0, stream>>>(
        counts, ranks, Nn, feat, featb, Wq, Wk, Wv, Wqkvt, W1, W1t, W2, W2t, dst, E, FB, WB);

    scanA_kernel<<<NCH, 256, 0, stream>>>(counts, bsum, Nn);
    scanC_kernel<<<NCH, 256, 0, stream>>>(counts, bsum, offsets, Nn, NCH);

    fill_qkv_kernel<<<CB + MP / 64, 256, 0, stream>>>(
        dst, src, ranks, offsets, srcs, E, CB, featb, Wqkvt, qb, kv8);

    agg_ln1_kernel<<<(Nn + 3) / 4, 256, 0, stream>>>(qb, kv8, feat,
                                                     srcs, offsets, ln1_g, ln1_b, rstb, Nn);

    ffn1_gemm<<<MP / 64, 256, 0, stream>>>(rstb, W1t, hid, b1, prelu);

    ffn2_ln2_kernel<<<MP / 64, 256, 0, stream>>>(hid, W2t, rstb, b2, ln2_g, ln2_b, out, Nn);
}

// Round 8
// 236.582 us; speedup vs baseline: 1.1815x; 1.1815x over previous
//
#include <hip/hip_runtime.h>
#include <hip/hip_bf16.h>
#include <math.h>

#define DIM 128
#define NHEAD 8
#define DHEAD 16
#define HID 512
#define LN_EPS 1e-5f
// (1/sqrt(128))*log2(e) folded into q so softmax runs in exp2 domain
#define QSCALE 0.12751879104863297f

typedef __bf16 bf16x8 __attribute__((ext_vector_type(8)));
typedef float f32x4 __attribute__((ext_vector_type(4)));
typedef float f32x2 __attribute__((ext_vector_type(2)));
typedef _Float16 f16x2 __attribute__((ext_vector_type(2)));

__device__ inline float bf2f(unsigned int bits16) {
    return __uint_as_float(bits16 << 16);
}
__device__ inline unsigned short f2bf(float f) {
    unsigned int u = __float_as_uint(f);
    unsigned int r = u + 0x7fff + ((u >> 16) & 1);   // RNE
    return (unsigned short)(r >> 16);
}
__device__ inline unsigned short f2h(float f) {
    _Float16 h = (_Float16)f;
    return __builtin_bit_cast(unsigned short, h);
}
__device__ inline float h2f(unsigned short h) {
    return (float)__builtin_bit_cast(_Float16, h);
}
// pack two floats -> two OCP e4m3 bytes (low ushort)
__device__ inline unsigned short pk_fp8(float a, float b) {
    int r = __builtin_amdgcn_cvt_pk_fp8_f32(a, b, 0, false);
    return (unsigned short)(r & 0xffff);
}
// unpack 2 fp8 bytes from low halfword
__device__ inline f32x2 unpk_fp8_lo(unsigned int w) {
    return __builtin_amdgcn_cvt_pk_f32_fp8((int)w, false);
}
__device__ inline f32x2 unpk_fp8_hi(unsigned int w) {
    return __builtin_amdgcn_cvt_pk_f32_fp8((int)w, true);
}
__device__ inline float fexp2(float x) { return __builtin_amdgcn_exp2f(x); }

// async global->LDS, 16B per lane
__device__ inline void gload_lds16(const void* g, void* l) {
    __builtin_amdgcn_global_load_lds(
        (const __attribute__((address_space(1))) unsigned int*)g,
        (__attribute__((address_space(3))) unsigned int*)l, 16, 0, 0);
}

// dot of 16 fp8 values (one uint4) against 16 floats, fully in-lane
__device__ __forceinline__ float dot16_fp8(uint4 w, const float (&q)[16]) {
    f32x2 a0 = unpk_fp8_lo(w.x), b0 = unpk_fp8_hi(w.x);
    f32x2 a1 = unpk_fp8_lo(w.y), b1 = unpk_fp8_hi(w.y);
    f32x2 a2 = unpk_fp8_lo(w.z), b2 = unpk_fp8_hi(w.z);
    f32x2 a3 = unpk_fp8_lo(w.w), b3 = unpk_fp8_hi(w.w);
    float t0 = fmaf(a0.x, q[0],  fmaf(a0.y, q[1],  fmaf(b0.x, q[2],  b0.y * q[3])));
    float t1 = fmaf(a1.x, q[4],  fmaf(a1.y, q[5],  fmaf(b1.x, q[6],  b1.y * q[7])));
    float t2 = fmaf(a2.x, q[8],  fmaf(a2.y, q[9],  fmaf(b2.x, q[10], b2.y * q[11])));
    float t3 = fmaf(a3.x, q[12], fmaf(a3.y, q[13], fmaf(b3.x, q[14], b3.y * q[15])));
    return (t0 + t1) + (t2 + t3);
}

// acc[j] += v_j * wt for 16 fp8 values (one uint4), fully in-lane
__device__ __forceinline__ void pv16_fp8(uint4 w, float wt, float (&acc)[16]) {
    f32x2 a0 = unpk_fp8_lo(w.x), b0 = unpk_fp8_hi(w.x);
    f32x2 a1 = unpk_fp8_lo(w.y), b1 = unpk_fp8_hi(w.y);
    f32x2 a2 = unpk_fp8_lo(w.z), b2 = unpk_fp8_hi(w.z);
    f32x2 a3 = unpk_fp8_lo(w.w), b3 = unpk_fp8_hi(w.w);
    acc[0]  = fmaf(a0.x, wt, acc[0]);  acc[1]  = fmaf(a0.y, wt, acc[1]);
    acc[2]  = fmaf(b0.x, wt, acc[2]);  acc[3]  = fmaf(b0.y, wt, acc[3]);
    acc[4]  = fmaf(a1.x, wt, acc[4]);  acc[5]  = fmaf(a1.y, wt, acc[5]);
    acc[6]  = fmaf(b1.x, wt, acc[6]);  acc[7]  = fmaf(b1.y, wt, acc[7]);
    acc[8]  = fmaf(a2.x, wt, acc[8]);  acc[9]  = fmaf(a2.y, wt, acc[9]);
    acc[10] = fmaf(b2.x, wt, acc[10]); acc[11] = fmaf(b2.y, wt, acc[11]);
    acc[12] = fmaf(a3.x, wt, acc[12]); acc[13] = fmaf(a3.y, wt, acc[13]);
    acc[14] = fmaf(b3.x, wt, acc[14]); acc[15] = fmaf(b3.y, wt, acc[15]);
}

// ---------------- k1: prep (feat->bf16, weight transposes) + count atomics + ranks ----------------
// counts zeroed by hipMemsetAsync before this kernel.
// blocks: [0,fb) featb | [fb,fb+192) Wqkv | +256 W1t | +256 W2t | [wb, wb+cb) count+rank
__global__ __launch_bounds__(256) void prep_count_kernel(
        int* counts, int* __restrict__ ranks, int Nn,
        const float* __restrict__ feat, unsigned short* __restrict__ featb,
        const float* __restrict__ Wq, const float* __restrict__ Wk, const float* __restrict__ Wv,
        unsigned short* __restrict__ Wqkvt,
        const float* __restrict__ W1, unsigned short* __restrict__ W1t,
        const float* __restrict__ W2, unsigned short* __restrict__ W2t,
        const int* __restrict__ dst, int E, int fb, int wb) {
    int blk = blockIdx.x, t = threadIdx.x;
    if (blk < fb) {
        int i = blk * 256 + t;            // quad index
        if (i < Nn * 32) {
            float4 v = *(const float4*)(feat + (size_t)i * 4);
            ushort4 o;
            o.x = f2bf(v.x); o.y = f2bf(v.y); o.z = f2bf(v.z); o.w = f2bf(v.w);
            *(ushort4*)(featb + (size_t)i * 4) = o;
        }
    } else if (blk < wb) {
        int b2_ = blk - fb;
        if (b2_ < 192) {
            int sec = b2_ >> 6;
            const float* W = sec == 0 ? Wq : (sec == 1 ? Wk : Wv);
            int o = (b2_ & 63) * 256 + t;
            int oc = o >> 7, orow = o & 127;
            Wqkvt[sec * 16384 + o] = f2bf(W[(size_t)orow * 128 + oc]);
        } else if (b2_ < 448) {
            int o = (b2_ - 192) * 256 + t;
            int oc = o >> 7, orow = o & 127;
            W1t[o] = f2bf(W1[(size_t)orow * 512 + oc]);
        } else {
            int o = (b2_ - 448) * 256 + t;
            int oc = o >> 9, orow = o & 511;
            W2t[o] = f2bf(W2[(size_t)orow * 128 + oc]);
        }
    } else {
        int e0 = (blk - wb) * 1024 + t * 4;
        if (e0 + 3 < E) {
            int4 d = *(const int4*)(dst + e0);
            int4 r;
            r.x = atomicAdd(&counts[d.x], 1);
            r.y = atomicAdd(&counts[d.y], 1);
            r.z = atomicAdd(&counts[d.z], 1);
            r.w = atomicAdd(&counts[d.w], 1);
            *(int4*)(ranks + e0) = r;
        } else {
            for (int e = e0; e < E; ++e) ranks[e] = atomicAdd(&counts[dst[e]], 1);
        }
    }
}

// ---------------- scan ----------------

__global__ __launch_bounds__(256) void scanA_kernel(const int* __restrict__ counts, int* bsum, int Nn) {
    int blk = blockIdx.x, t = threadIdx.x;
    int i = blk * 1024 + t * 4;
    int s = 0;
    if (i < Nn) { int4 x = *(const int4*)(counts + i); s = x.x + x.y + x.z + x.w; }
#pragma unroll
    for (int off = 1; off < 64; off <<= 1) s += __shfl_xor(s, off, 64);
    __shared__ int wt[4];
    if ((t & 63) == 0) wt[t >> 6] = s;
    __syncthreads();
    if (t == 0) bsum[blk] = wt[0] + wt[1] + wt[2] + wt[3];
}

__global__ __launch_bounds__(256) void scanC_kernel(const int* __restrict__ counts, const int* __restrict__ bsum,
                                                    int* offsets, int Nn, int NCH) {
    int blk = blockIdx.x, t = threadIdx.x, lane = t & 63, wv = t >> 6;
    __shared__ int wt[4];
    __shared__ int base_s;
    if (wv == 0) {
        int v = (lane < NCH) ? bsum[lane] : 0;
        int s = v;
#pragma unroll
        for (int off = 1; off < 64; off <<= 1) {
            int u = __shfl_up(s, off, 64);
            if (lane >= off) s += u;
        }
        int basev = (blk > 0) ? __shfl(s, blk - 1, 64) : 0;
        int tot = __shfl(s, NCH - 1, 64);
        if (lane == 0) {
            base_s = basev;
            if (blk == 0) offsets[Nn] = tot;
        }
    }
    int i = blk * 1024 + t * 4;
    int4 x = make_int4(0, 0, 0, 0);
    if (i < Nn) x = *(const int4*)(counts + i);
    int ts = x.x + x.y + x.z + x.w;
    int s = ts;
#pragma unroll
    for (int off = 1; off < 64; off <<= 1) {
        int u = __shfl_up(s, off, 64);
        if (lane >= off) s += u;
    }
    if (lane == 63) wt[wv] = s;
    __syncthreads();
    int woff = 0;
    for (int wi = 0; wi < wv; ++wi) woff += wt[wi];
    int excl = base_s + woff + (s - ts);
    if (i < Nn) {
        int o0 = excl, o1 = o0 + x.x, o2 = o1 + x.y, o3 = o2 + x.z;
        *(int4*)(offsets + i) = make_int4(o0, o1, o2, o3);
    }
}

// ---------------- k4: fill (CSR scatter, no atomics) + qkv GEMM ----------------
// blocks [0, cb): fill; blocks [cb, cb+3*MB): qkv (region = q%3, mtile = q/3)
// q: f16 pre-scaled [node][128]. kv8: per node 256B = 128B k-fp8 | 128B v-fp8.
#define QST 136
__global__ __launch_bounds__(256) void fill_qkv_kernel(
        const int* __restrict__ dst, const int* __restrict__ src,
        const int* __restrict__ ranks, const int* __restrict__ offsets,
        int* __restrict__ srcs, int E, int cb,
        const unsigned short* __restrict__ A, const unsigned short* __restrict__ Bt,
        unsigned short* __restrict__ qb, unsigned char* __restrict__ kv8) {
    int blk = blockIdx.x, t = threadIdx.x;
    if (blk < cb) {
        int e0 = blk * 1024 + t * 4;
        if (e0 + 3 < E) {
            int4 d = *(const int4*)(dst + e0);
            int4 sv = *(const int4*)(src + e0);
            int4 rk = *(const int4*)(ranks + e0);
            srcs[offsets[d.x] + rk.x] = sv.x;
            srcs[offsets[d.y] + rk.y] = sv.y;
            srcs[offsets[d.z] + rk.z] = sv.z;
            srcs[offsets[d.w] + rk.w] = sv.w;
        } else {
            for (int e = e0; e < E; ++e) srcs[offsets[dst[e]] + ranks[e]] = src[e];
        }
        return;
    }
    __shared__ unsigned short smem[128 * QST];
    unsigned short* As = smem;
    unsigned short* Bs = smem + 4096;
    int q = blk - cb;
    int region = q % 3;
    int m0 = (q / 3) * 128;
    int wave = t >> 6, lane = t & 63;
    int wr = wave >> 1, wc = wave & 1;
    int lrow = lane & 15, kq = lane >> 4;
    int n0 = region * 128;
    int srow = t >> 2, scol8 = (t & 3) * 8;

    f32x4 acc[4][4] = {};
    for (int k0 = 0; k0 < 128; k0 += 32) {
        gload_lds16(A + (size_t)(m0 + srow) * 128 + k0 + scol8,      As + t * 8);
        gload_lds16(A + (size_t)(m0 + 64 + srow) * 128 + k0 + scol8, As + 2048 + t * 8);
        gload_lds16(Bt + (size_t)(n0 + srow) * 128 + k0 + scol8,      Bs + t * 8);
        gload_lds16(Bt + (size_t)(n0 + 64 + srow) * 128 + k0 + scol8, Bs + 2048 + t * 8);
        __syncthreads();
        bf16x8 af[4], bfr[4];
#pragma unroll
        for (int mi = 0; mi < 4; ++mi)
            af[mi] = *(const bf16x8*)(&As[(wr * 64 + mi * 16 + lrow) * 32 + kq * 8]);
#pragma unroll
        for (int ni = 0; ni < 4; ++ni)
            bfr[ni] = *(const bf16x8*)(&Bs[(wc * 64 + ni * 16 + lrow) * 32 + kq * 8]);
#pragma unroll
        for (int mi = 0; mi < 4; ++mi)
#pragma unroll
            for (int ni = 0; ni < 4; ++ni)
                acc[mi][ni] = __builtin_amdgcn_mfma_f32_16x16x32_bf16(af[mi], bfr[ni], acc[mi][ni], 0, 0, 0);
        __syncthreads();
    }

    float scale = (region == 0) ? QSCALE : 1.f;
#pragma unroll
    for (int ni = 0; ni < 4; ++ni) {
        int col = wc * 64 + ni * 16 + lrow;
#pragma unroll
        for (int mi = 0; mi < 4; ++mi) {
#pragma unroll
            for (int r = 0; r < 4; ++r) {
                int row = wr * 64 + mi * 16 + kq * 4 + r;
                smem[row * QST + col] = f2h(acc[mi][ni][r] * scale);
            }
        }
    }
    __syncthreads();
    if (region == 0) {
        unsigned short* outp = qb + (size_t)m0 * 128;
#pragma unroll
        for (int i = 0; i < 8; ++i) {
            int chunk = i * 256 + t;
            int row = chunk >> 4, c16 = chunk & 15;
            *(float4*)(outp + (size_t)chunk * 8) = *(const float4*)(smem + row * QST + c16 * 8);
        }
    } else {
        // fp8 convert + coalesced 16B stores: 128 rows x 8 chunks of 16 dims
        int half = region - 1;   // 0:k, 1:v
#pragma unroll
        for (int i = 0; i < 4; ++i) {
            int chunk = i * 256 + t;         // 0..1023
            int row = chunk >> 3, seg = chunk & 7;
            const unsigned short* sp = smem + row * QST + seg * 16;
            unsigned int ow[4];
#pragma unroll
            for (int j = 0; j < 4; ++j) {
                unsigned int lo = pk_fp8(h2f(sp[4 * j]), h2f(sp[4 * j + 1]));
                unsigned int hi = pk_fp8(h2f(sp[4 * j + 2]), h2f(sp[4 * j + 3]));
                ow[j] = lo | (hi << 16);
            }
            *(uint4*)(kv8 + (size_t)(m0 + row) * 256 + half * 128 + seg * 16) =
                make_uint4(ow[0], ow[1], ow[2], ow[3]);
        }
    }
}

// ---------------- k5: fused attention aggregate + residual + LN1 ----------------
// one wave per node; lane = (edge_slot e = lane>>3, head h = lane&7).
// srcs for iteration i+1 prefetched during iteration i: breaks the serial
// srcs-load -> kv-gather two-hop chain (kv gathers issue at loop top).
__global__ __launch_bounds__(256) void agg_ln1_kernel(
        const unsigned short* __restrict__ qb, const unsigned char* __restrict__ kv8,
        const float* __restrict__ feat,
        const int* __restrict__ srcs, const int* __restrict__ offsets,
        const float* __restrict__ g, const float* __restrict__ b,
        unsigned short* __restrict__ rstb, int n) {
    int node = blockIdx.x * 4 + (threadIdx.x >> 6);
    int lane = threadIdx.x & 63;
    if (node >= n) return;
    int el = lane >> 3;      // edge slot 0..7
    int h  = lane & 7;       // head 0..7

    // q for this head: 16 f16 (pre-scaled by QSCALE*log2e) -> 16 floats
    const uint4* qp = (const uint4*)(qb + (size_t)node * 128 + h * 16);
    uint4 qlo = qp[0], qhi = qp[1];
    float qf[16];
    {
        unsigned int qw[8] = {qlo.x, qlo.y, qlo.z, qlo.w, qhi.x, qhi.y, qhi.z, qhi.w};
#pragma unroll
        for (int j = 0; j < 8; ++j) {
            f16x2 p2 = __builtin_bit_cast(f16x2, qw[j]);
            qf[2 * j]     = (float)p2.x;
            qf[2 * j + 1] = (float)p2.y;
        }
    }

    int beg = offsets[node], end = offsets[node + 1];
    float l = 0.f;
    float acc[16];
#pragma unroll
    for (int j = 0; j < 16; ++j) acc[j] = 0.f;

    // prefetch first iteration's srcs
    int s0p = 0, s1p = 0;
    if (beg < end) {
        int e0i = beg + el, e1i = beg + 8 + el;
        s0p = srcs[(e0i < end) ? e0i : beg];
        s1p = srcs[(e1i < end) ? e1i : beg];
    }

    // 16 edges per iteration: 2 slots per lane; next iter's srcs prefetched early
    for (int idx = beg; idx < end; idx += 16) {
        int s0 = s0p, s1 = s1p;
        bool v0 = (idx + el) < end, v1 = (idx + 8 + el) < end;
        int nx = idx + 16;
        if (nx < end) {
            int e0i = nx + el, e1i = nx + 8 + el;
            s0p = srcs[(e0i < end) ? e0i : beg];
            s1p = srcs[(e1i < end) ? e1i : beg];
        }
        const uint4* kp0 = (const uint4*)(kv8 + (size_t)s0 * 256 + h * 16);
        const uint4* kp1 = (const uint4*)(kv8 + (size_t)s1 * 256 + h * 16);
        uint4 kw0 = kp0[0];
        uint4 vw0 = kp0[8];     // +128B
        uint4 kw1 = kp1[0];
        uint4 vw1 = kp1[8];

        float p0 = dot16_fp8(kw0, qf);
        float p1 = dot16_fp8(kw1, qf);
        float sc0 = v0 ? fminf(fmaxf(p0, -30.f), 30.f) : -1000.f;
        float sc1 = v1 ? fminf(fmaxf(p1, -30.f), 30.f) : -1000.f;
        float w0 = fexp2(sc0);
        float w1 = fexp2(sc1);
        l += w0 + w1;
        pv16_fp8(vw0, w0, acc);
        pv16_fp8(vw1, w1, acc);
    }

    // all-reduce softmax denom across the 8 edge-lanes (lane bits 3,4,5)
    l += __shfl_xor(l, 8, 64);
    l += __shfl_xor(l, 16, 64);
    l += __shfl_xor(l, 32, 64);

    // reduce-scatter acc over edge-lanes: each round halves dims, selects by e-bit
    float r8[8];
    {
        bool b0 = (el & 1) != 0;
#pragma unroll
        for (int j = 0; j < 8; ++j) {
            float send = b0 ? acc[j] : acc[j + 8];
            float keep = b0 ? acc[j + 8] : acc[j];
            r8[j] = keep + __shfl_xor(send, 8, 64);
        }
    }
    float r4[4];
    {
        bool b1 = (el & 2) != 0;
#pragma unroll
        for (int j = 0; j < 4; ++j) {
            float send = b1 ? r8[j] : r8[j + 4];
            float keep = b1 ? r8[j + 4] : r8[j];
            r4[j] = keep + __shfl_xor(send, 16, 64);
        }
    }
    float r2[2];
    {
        bool b2 = (el & 4) != 0;
#pragma unroll
        for (int j = 0; j < 2; ++j) {
            float send = b2 ? r4[j] : r4[j + 2];
            float keep = b2 ? r4[j + 2] : r4[j];
            r2[j] = keep + __shfl_xor(send, 32, 64);
        }
    }
    // lane now owns dims d0, d0+1 with d0 = h*16 + 8*e0 + 4*e1 + 2*e2
    int off = ((el & 1) << 3) | ((el & 2) << 1) | ((el & 4) >> 1);
    int d0 = h * 16 + off;

    float inv = (l > 0.f) ? 1.f / l : 0.f;
    float2 fv = *(const float2*)(feat + (size_t)node * DIM + d0);
    float x0 = r2[0] * inv + fv.x;
    float x1 = r2[1] * inv + fv.y;

    float s1 = x0 + x1;
    float s2 = x0 * x0 + x1 * x1;
#pragma unroll
    for (int off2 = 1; off2 < 64; off2 <<= 1) {
        s1 += __shfl_xor(s1, off2, 64);
        s2 += __shfl_xor(s2, off2, 64);
    }
    float mean = s1 * (1.f / DIM);
    float var = s2 * (1.f / DIM) - mean * mean;
    float rinv = rsqrtf(var + LN_EPS);
    float2 gv = *(const float2*)(g + d0);
    float2 bv = *(const float2*)(b + d0);
    float o0 = (x0 - mean) * rinv * gv.x + bv.x;
    float o1 = (x1 - mean) * rinv * gv.y + bv.y;
    unsigned int packed = (unsigned int)f2bf(o0) | ((unsigned int)f2bf(o1) << 16);
    ((unsigned int*)rstb)[(size_t)node * 64 + (d0 >> 1)] = packed;
}

// ---------------- k6: FFN1: hid = PReLU(rst @ W1 + b1), bf16 out ----------------
__global__ __launch_bounds__(256) void ffn1_gemm(
        const unsigned short* __restrict__ A, const unsigned short* __restrict__ Bt,
        unsigned short* __restrict__ hid,
        const float* __restrict__ b1, const float* __restrict__ prelu) {
    __shared__ unsigned short smem[128 * QST];
    unsigned short* As = smem;
    unsigned short* Bs = smem + 4096;
    int t = threadIdx.x;
    int wave = t >> 6, lane = t & 63;
    int wr = wave >> 1, wc = wave & 1;
    int lrow = lane & 15, kq = lane >> 4;
    int m0 = blockIdx.y * 128;
    int n0 = blockIdx.x * 128;
    int srow = t >> 2, scol8 = (t & 3) * 8;

    f32x4 acc[4][4] = {};
    for (int k0 = 0; k0 < 128; k0 += 32) {
        gload_lds16(A + (size_t)(m0 + srow) * 128 + k0 + scol8,      As + t * 8);
        gload_lds16(A + (size_t)(m0 + 64 + srow) * 128 + k0 + scol8, As + 2048 + t * 8);
        gload_lds16(Bt + (size_t)(n0 + srow) * 128 + k0 + scol8,      Bs + t * 8);
        gload_lds16(Bt + (size_t)(n0 + 64 + srow) * 128 + k0 + scol8, Bs + 2048 + t * 8);
        __syncthreads();
        bf16x8 af[4], bfr[4];
#pragma unroll
        for (int mi = 0; mi < 4; ++mi)
            af[mi] = *(const bf16x8*)(&As[(wr * 64 + mi * 16 + lrow) * 32 + kq * 8]);
#pragma unroll
        for (int ni = 0; ni < 4; ++ni)
            bfr[ni] = *(const bf16x8*)(&Bs[(wc * 64 + ni * 16 + lrow) * 32 + kq * 8]);
#pragma unroll
        for (int mi = 0; mi < 4; ++mi)
#pragma unroll
            for (int ni = 0; ni < 4; ++ni)
                acc[mi][ni] = __builtin_amdgcn_mfma_f32_16x16x32_bf16(af[mi], bfr[ni], acc[mi][ni], 0, 0, 0);
        __syncthreads();
    }

#pragma unroll
    for (int ni = 0; ni < 4; ++ni) {
        int col = wc * 64 + ni * 16 + lrow;
        int cg = n0 + col;
        float biv = b1[cg], pwv = prelu[cg];
#pragma unroll
        for (int mi = 0; mi < 4; ++mi) {
#pragma unroll
            for (int r = 0; r < 4; ++r) {
                int row = wr * 64 + mi * 16 + kq * 4 + r;
                float v = acc[mi][ni][r] + biv;
                v = v >= 0.f ? v : pwv * v;
                smem[row * QST + col] = f2bf(v);
            }
        }
    }
    __syncthreads();
#pragma unroll
    for (int i = 0; i < 8; ++i) {
        int chunk = i * 256 + t;
        int row = chunk >> 4, c16 = chunk & 15;
        *(float4*)(hid + (size_t)(m0 + row) * 512 + n0 + c16 * 8) =
            *(const float4*)(smem + row * QST + c16 * 8);
    }
}

// ---------------- k7: FFN2 + residual + LN2 ----------------
// grid (MP/64): 64-row tiles; wave w owns cols [w*32, w*32+32); two-phase LN reduction.
__global__ __launch_bounds__(256) void ffn2_ln2_kernel(
        const unsigned short* __restrict__ hid, const unsigned short* __restrict__ W2t,
        const unsigned short* __restrict__ rstb,
        const float* __restrict__ b2, const float* __restrict__ g, const float* __restrict__ bb,
        float* __restrict__ out, int Nn) {
    __shared__ unsigned short As[64 * 32];
    __shared__ unsigned short Bs[128 * 32];
    __shared__ float redS[64][4];
    __shared__ float redQ[64][4];
    int t = threadIdx.x;
    int wave = t >> 6, lane = t & 63;
    int lrow = lane & 15, kq = lane >> 4;
    int m0 = blockIdx.x * 64;
    int srow = t >> 2, scol8 = (t & 3) * 8;

    f32x4 acc[4][2] = {};
    for (int k0 = 0; k0 < 512; k0 += 32) {
        gload_lds16(hid + (size_t)(m0 + srow) * 512 + k0 + scol8, As + t * 8);
        gload_lds16(W2t + (size_t)srow * 512 + k0 + scol8,        Bs + t * 8);
        gload_lds16(W2t + (size_t)(64 + srow) * 512 + k0 + scol8, Bs + 2048 + t * 8);
        __syncthreads();
        bf16x8 af[4], bfr[2];
#pragma unroll
        for (int mi = 0; mi < 4; ++mi)
            af[mi] = *(const bf16x8*)(&As[(mi * 16 + lrow) * 32 + kq * 8]);
#pragma unroll
        for (int ni = 0; ni < 2; ++ni)
            bfr[ni] = *(const bf16x8*)(&Bs[(wave * 32 + ni * 16 + lrow) * 32 + kq * 8]);
#pragma unroll
        for (int mi = 0; mi < 4; ++mi)
#pragma unroll
            for (int ni = 0; ni < 2; ++ni)
                acc[mi][ni] = __builtin_amdgcn_mfma_f32_16x16x32_bf16(af[mi], bfr[ni], acc[mi][ni], 0, 0, 0);
        __syncthreads();
    }

    float b2v[2], gv[2], bv[2];
    int cols[2];
#pragma unroll
    for (int ni = 0; ni < 2; ++ni) {
        cols[ni] = wave * 32 + ni * 16 + lrow;
        b2v[ni] = b2[cols[ni]]; gv[ni] = g[cols[ni]]; bv[ni] = bb[cols[ni]];
    }
#pragma unroll
    for (int mi = 0; mi < 4; ++mi) {
#pragma unroll
        for (int r = 0; r < 4; ++r) {
            int rloc = mi * 16 + kq * 4 + r;
            int row = m0 + rloc;
            float ps = 0.f, pq = 0.f;
#pragma unroll
            for (int ni = 0; ni < 2; ++ni) {
                float rsv = bf2f(rstb[(size_t)row * 128 + cols[ni]]);
                float v = acc[mi][ni][r] + b2v[ni] + rsv;
                acc[mi][ni][r] = v;
                ps += v; pq += v * v;
            }
#pragma unroll
            for (int off = 1; off < 16; off <<= 1) {
                ps += __shfl_xor(ps, off, 16);
                pq += __shfl_xor(pq, off, 16);
            }
            if (lrow == 0) { redS[rloc][wave] = ps; redQ[rloc][wave] = pq; }
        }
    }
    __syncthreads();
#pragma unroll
    for (int mi = 0; mi < 4; ++mi) {
#pragma unroll
        for (int r = 0; r < 4; ++r) {
            int rloc = mi * 16 + kq * 4 + r;
            int row = m0 + rloc;
            float s1 = redS[rloc][0] + redS[rloc][1] + redS[rloc][2] + redS[rloc][3];
            float sq = redQ[rloc][0] + redQ[rloc][1] + redQ[rloc][2] + redQ[rloc][3];
            float mean = s1 * (1.f / DIM);
            float var = sq * (1.f / DIM) - mean * mean;
            float rs = rsqrtf(var + LN_EPS);
            if (row < Nn) {
#pragma unroll
                for (int ni = 0; ni < 2; ++ni)
                    out[(size_t)row * 128 + cols[ni]] =
                        (acc[mi][ni][r] - mean) * rs * gv[ni] + bv[ni];
            }
        }
    }
}

// ---------------- launch ----------------

extern "C" void kernel_launch(void* const* d_in, const int* in_sizes, int n_in,
                              void* d_out, int out_size, void* d_ws, size_t ws_size,
                              hipStream_t stream) {
    const float* feat   = (const float*)d_in[0];
    const int*   src    = (const int*)d_in[1];
    const int*   dst    = (const int*)d_in[2];
    const float* Wq     = (const float*)d_in[3];
    const float* Wk     = (const float*)d_in[4];
    const float* Wv     = (const float*)d_in[5];
    const float* ln1_g  = (const float*)d_in[6];
    const float* ln1_b  = (const float*)d_in[7];
    const float* ln2_g  = (const float*)d_in[8];
    const float* ln2_b  = (const float*)d_in[9];
    const float* W1     = (const float*)d_in[10];
    const float* b1     = (const float*)d_in[11];
    const float* prelu  = (const float*)d_in[12];
    const float* W2     = (const float*)d_in[13];
    const float* b2     = (const float*)d_in[14];
    float* out = (float*)d_out;

    const int Nn = in_sizes[0] / DIM;        // 40000
    const int E  = in_sizes[1];              // 640000
    const int MP = (Nn + 127) & ~127;        // 40064

    char* w = (char*)d_ws;
    unsigned short* qb   = (unsigned short*)w; w += (size_t)MP * DIM * 2;
    unsigned char*  kv8  = (unsigned char*)w;  w += (size_t)MP * 256;   // 128B k | 128B v per node
    unsigned short* rstb = (unsigned short*)w; w += (size_t)MP * DIM * 2;
    unsigned short* featb= (unsigned short*)w; w += (size_t)MP * DIM * 2;
    unsigned short* hid  = (unsigned short*)w; w += (size_t)MP * HID * 2;
    unsigned short* Wqkvt= (unsigned short*)w; w += 3 * DIM * DIM * 2;
    unsigned short* W1t  = (unsigned short*)w; w += (size_t)HID * DIM * 2;
    unsigned short* W2t  = (unsigned short*)w; w += (size_t)DIM * HID * 2;
    int* counts  = (int*)w;  w += (size_t)Nn * 4;
    int* offsets = (int*)w;  w += (size_t)(Nn + 4) * 4;
    int* bsum    = (int*)w;  w += 64 * 4;
    int* srcs    = (int*)w;
    // ranks aliases hid: hid written by ffn1 only AFTER fill_qkv consumed ranks
    int* ranks   = (int*)hid;

    const int NCH = (Nn + 1023) / 1024;      // 40 (<= 64)
    const int FB  = Nn / 8;                  // featb blocks (Nn*32 quads / 256)
    const int WB  = FB + 704;                // + weight transpose blocks
    const int CB  = (E + 1023) / 1024;       // count/fill blocks

    hipMemsetAsync(counts, 0, (size_t)Nn * 4, stream);
    // hygiene: zero padding rows [Nn, MP) of featb and rstb (read as GEMM A-tiles
    // by padding tiles)
    if (MP > Nn) {
        hipMemsetAsync(featb + (size_t)Nn * DIM, 0, (size_t)(MP - Nn) * DIM * 2, stream);
        hipMemsetAsync(rstb + (size_t)Nn * DIM, 0, (size_t)(MP - Nn) * DIM * 2, stream);
    }

    prep_count_kernel<<<WB + CB, 256, 0, stream>>>(
        counts, ranks, Nn, feat, featb, Wq, Wk, Wv, Wqkvt, W1, W1t, W2, W2t, dst, E, FB, WB);

    scanA_kernel<<<NCH, 256, 0, stream>>>(counts, bsum, Nn);
    scanC_kernel<<<NCH, 256, 0, stream>>>(counts, bsum, offsets, Nn, NCH);

    fill_qkv_kernel<<<CB + 3 * (MP / 128), 256, 0, stream>>>(
        dst, src, ranks, offsets, srcs, E, CB, featb, Wqkvt, qb, kv8);

    agg_ln1_kernel<<<(Nn + 3) / 4, 256, 0, stream>>>(qb, kv8, feat,
                                                     srcs, offsets, ln1_g, ln1_b, rstb, Nn);

    {
        dim3 grid(4, MP / 128);
        ffn1_gemm<<<grid, 256, 0, stream>>>(rstb, W1t, hid, b1, prelu);
    }

    ffn2_ln2_kernel<<<MP / 64, 256, 0, stream>>>(hid, W2t, rstb, b2, ln2_g, ln2_b, out, Nn);
}

// Round 9
// 230.659 us; speedup vs baseline: 1.2118x; 1.0257x over previous
//
#include <hip/hip_runtime.h>
#include <hip/hip_bf16.h>
#include <math.h>

#define DIM 128
#define NHEAD 8
#define DHEAD 16
#define HID 512
#define LN_EPS 1e-5f
// (1/sqrt(128))*log2(e) folded into q so softmax runs in exp2 domain
#define QSCALE 0.12751879104863297f

typedef __bf16 bf16x8 __attribute__((ext_vector_type(8)));
typedef float f32x4 __attribute__((ext_vector_type(4)));
typedef float f32x2 __attribute__((ext_vector_type(2)));
typedef _Float16 f16x2 __attribute__((ext_vector_type(2)));

__device__ inline float bf2f(unsigned int bits16) {
    return __uint_as_float(bits16 << 16);
}
__device__ inline unsigned short f2bf(float f) {
    unsigned int u = __float_as_uint(f);
    unsigned int r = u + 0x7fff + ((u >> 16) & 1);   // RNE
    return (unsigned short)(r >> 16);
}
__device__ inline unsigned short f2h(float f) {
    _Float16 h = (_Float16)f;
    return __builtin_bit_cast(unsigned short, h);
}
__device__ inline float h2f(unsigned short h) {
    return (float)__builtin_bit_cast(_Float16, h);
}
// pack two floats -> two OCP e4m3 bytes (low ushort)
__device__ inline unsigned short pk_fp8(float a, float b) {
    int r = __builtin_amdgcn_cvt_pk_fp8_f32(a, b, 0, false);
    return (unsigned short)(r & 0xffff);
}
// unpack 2 fp8 bytes from low/high halfword
__device__ inline f32x2 unpk_fp8_lo(unsigned int w) {
    return __builtin_amdgcn_cvt_pk_f32_fp8((int)w, false);
}
__device__ inline f32x2 unpk_fp8_hi(unsigned int w) {
    return __builtin_amdgcn_cvt_pk_f32_fp8((int)w, true);
}
__device__ inline float fexp2(float x) { return __builtin_amdgcn_exp2f(x); }

// async global->LDS, 16B per lane
__device__ inline void gload_lds16(const void* g, void* l) {
    __builtin_amdgcn_global_load_lds(
        (const __attribute__((address_space(1))) unsigned int*)g,
        (__attribute__((address_space(3))) unsigned int*)l, 16, 0, 0);
}

// dot of 16 fp8 values (one uint4) against 16 floats, fully in-lane
__device__ __forceinline__ float dot16_fp8(uint4 w, const float (&q)[16]) {
    f32x2 a0 = unpk_fp8_lo(w.x), b0 = unpk_fp8_hi(w.x);
    f32x2 a1 = unpk_fp8_lo(w.y), b1 = unpk_fp8_hi(w.y);
    f32x2 a2 = unpk_fp8_lo(w.z), b2 = unpk_fp8_hi(w.z);
    f32x2 a3 = unpk_fp8_lo(w.w), b3 = unpk_fp8_hi(w.w);
    float t0 = fmaf(a0.x, q[0],  fmaf(a0.y, q[1],  fmaf(b0.x, q[2],  b0.y * q[3])));
    float t1 = fmaf(a1.x, q[4],  fmaf(a1.y, q[5],  fmaf(b1.x, q[6],  b1.y * q[7])));
    float t2 = fmaf(a2.x, q[8],  fmaf(a2.y, q[9],  fmaf(b2.x, q[10], b2.y * q[11])));
    float t3 = fmaf(a3.x, q[12], fmaf(a3.y, q[13], fmaf(b3.x, q[14], b3.y * q[15])));
    return (t0 + t1) + (t2 + t3);
}

// acc[j] += v_j * wt for 16 fp8 values (one uint4), fully in-lane
__device__ __forceinline__ void pv16_fp8(uint4 w, float wt, float (&acc)[16]) {
    f32x2 a0 = unpk_fp8_lo(w.x), b0 = unpk_fp8_hi(w.x);
    f32x2 a1 = unpk_fp8_lo(w.y), b1 = unpk_fp8_hi(w.y);
    f32x2 a2 = unpk_fp8_lo(w.z), b2 = unpk_fp8_hi(w.z);
    f32x2 a3 = unpk_fp8_lo(w.w), b3 = unpk_fp8_hi(w.w);
    acc[0]  = fmaf(a0.x, wt, acc[0]);  acc[1]  = fmaf(a0.y, wt, acc[1]);
    acc[2]  = fmaf(b0.x, wt, acc[2]);  acc[3]  = fmaf(b0.y, wt, acc[3]);
    acc[4]  = fmaf(a1.x, wt, acc[4]);  acc[5]  = fmaf(a1.y, wt, acc[5]);
    acc[6]  = fmaf(b1.x, wt, acc[6]);  acc[7]  = fmaf(b1.y, wt, acc[7]);
    acc[8]  = fmaf(a2.x, wt, acc[8]);  acc[9]  = fmaf(a2.y, wt, acc[9]);
    acc[10] = fmaf(b2.x, wt, acc[10]); acc[11] = fmaf(b2.y, wt, acc[11]);
    acc[12] = fmaf(a3.x, wt, acc[12]); acc[13] = fmaf(a3.y, wt, acc[13]);
    acc[14] = fmaf(b3.x, wt, acc[14]); acc[15] = fmaf(b3.y, wt, acc[15]);
}

// ---------------- k1: prep (feat->bf16, weight transposes) + count atomics + ranks ----------------
// counts zeroed by hipMemsetAsync before this kernel.
// blocks: [0,fb) featb | [fb,fb+192) Wqkv | +256 W1t | +256 W2t | [wb, wb+cb) count+rank
__global__ __launch_bounds__(256) void prep_count_kernel(
        int* counts, int* __restrict__ ranks, int Nn,
        const float* __restrict__ feat, unsigned short* __restrict__ featb,
        const float* __restrict__ Wq, const float* __restrict__ Wk, const float* __restrict__ Wv,
        unsigned short* __restrict__ Wqkvt,
        const float* __restrict__ W1, unsigned short* __restrict__ W1t,
        const float* __restrict__ W2, unsigned short* __restrict__ W2t,
        const int* __restrict__ dst, int E, int fb, int wb) {
    int blk = blockIdx.x, t = threadIdx.x;
    if (blk < fb) {
        int i = blk * 256 + t;            // quad index
        if (i < Nn * 32) {
            float4 v = *(const float4*)(feat + (size_t)i * 4);
            ushort4 o;
            o.x = f2bf(v.x); o.y = f2bf(v.y); o.z = f2bf(v.z); o.w = f2bf(v.w);
            *(ushort4*)(featb + (size_t)i * 4) = o;
        }
    } else if (blk < wb) {
        int b2_ = blk - fb;
        if (b2_ < 192) {
            int sec = b2_ >> 6;
            const float* W = sec == 0 ? Wq : (sec == 1 ? Wk : Wv);
            int o = (b2_ & 63) * 256 + t;
            int oc = o >> 7, orow = o & 127;
            Wqkvt[sec * 16384 + o] = f2bf(W[(size_t)orow * 128 + oc]);
        } else if (b2_ < 448) {
            int o = (b2_ - 192) * 256 + t;
            int oc = o >> 7, orow = o & 127;
            W1t[o] = f2bf(W1[(size_t)orow * 512 + oc]);
        } else {
            int o = (b2_ - 448) * 256 + t;
            int oc = o >> 9, orow = o & 511;
            W2t[o] = f2bf(W2[(size_t)orow * 128 + oc]);
        }
    } else {
        int e0 = (blk - wb) * 1024 + t * 4;
        if (e0 + 3 < E) {
            int4 d = *(const int4*)(dst + e0);
            int4 r;
            r.x = atomicAdd(&counts[d.x], 1);
            r.y = atomicAdd(&counts[d.y], 1);
            r.z = atomicAdd(&counts[d.z], 1);
            r.w = atomicAdd(&counts[d.w], 1);
            *(int4*)(ranks + e0) = r;
        } else {
            for (int e = e0; e < E; ++e) ranks[e] = atomicAdd(&counts[dst[e]], 1);
        }
    }
}

// ---------------- scan ----------------

__global__ __launch_bounds__(256) void scanA_kernel(const int* __restrict__ counts, int* bsum, int Nn) {
    int blk = blockIdx.x, t = threadIdx.x;
    int i = blk * 1024 + t * 4;
    int s = 0;
    if (i < Nn) { int4 x = *(const int4*)(counts + i); s = x.x + x.y + x.z + x.w; }
#pragma unroll
    for (int off = 1; off < 64; off <<= 1) s += __shfl_xor(s, off, 64);
    __shared__ int wt[4];
    if ((t & 63) == 0) wt[t >> 6] = s;
    __syncthreads();
    if (t == 0) bsum[blk] = wt[0] + wt[1] + wt[2] + wt[3];
}

__global__ __launch_bounds__(256) void scanC_kernel(const int* __restrict__ counts, const int* __restrict__ bsum,
                                                    int* offsets, int Nn, int NCH) {
    int blk = blockIdx.x, t = threadIdx.x, lane = t & 63, wv = t >> 6;
    __shared__ int wt[4];
    __shared__ int base_s;
    if (wv == 0) {
        int v = (lane < NCH) ? bsum[lane] : 0;
        int s = v;
#pragma unroll
        for (int off = 1; off < 64; off <<= 1) {
            int u = __shfl_up(s, off, 64);
            if (lane >= off) s += u;
        }
        int basev = (blk > 0) ? __shfl(s, blk - 1, 64) : 0;
        int tot = __shfl(s, NCH - 1, 64);
        if (lane == 0) {
            base_s = basev;
            if (blk == 0) offsets[Nn] = tot;
        }
    }
    int i = blk * 1024 + t * 4;
    int4 x = make_int4(0, 0, 0, 0);
    if (i < Nn) x = *(const int4*)(counts + i);
    int ts = x.x + x.y + x.z + x.w;
    int s = ts;
#pragma unroll
    for (int off = 1; off < 64; off <<= 1) {
        int u = __shfl_up(s, off, 64);
        if (lane >= off) s += u;
    }
    if (lane == 63) wt[wv] = s;
    __syncthreads();
    int woff = 0;
    for (int wi = 0; wi < wv; ++wi) woff += wt[wi];
    int excl = base_s + woff + (s - ts);
    if (i < Nn) {
        int o0 = excl, o1 = o0 + x.x, o2 = o1 + x.y, o3 = o2 + x.z;
        *(int4*)(offsets + i) = make_int4(o0, o1, o2, o3);
    }
}

// ---------------- k4: fill (CSR scatter, no atomics) + qkv GEMM ----------------
// blocks [0, cb): fill; blocks [cb, cb+3*MB): qkv (region = q%3, mtile = q/3)
// q: f16 pre-scaled [node][128]. kv8: per node 256B = 128B k-fp8 | 128B v-fp8.
#define QST 136
__global__ __launch_bounds__(256) void fill_qkv_kernel(
        const int* __restrict__ dst, const int* __restrict__ src,
        const int* __restrict__ ranks, const int* __restrict__ offsets,
        int* __restrict__ srcs, int E, int cb,
        const unsigned short* __restrict__ A, const unsigned short* __restrict__ Bt,
        unsigned short* __restrict__ qb, unsigned char* __restrict__ kv8) {
    int blk = blockIdx.x, t = threadIdx.x;
    if (blk < cb) {
        int e0 = blk * 1024 + t * 4;
        if (e0 + 3 < E) {
            int4 d = *(const int4*)(dst + e0);
            int4 sv = *(const int4*)(src + e0);
            int4 rk = *(const int4*)(ranks + e0);
            srcs[offsets[d.x] + rk.x] = sv.x;
            srcs[offsets[d.y] + rk.y] = sv.y;
            srcs[offsets[d.z] + rk.z] = sv.z;
            srcs[offsets[d.w] + rk.w] = sv.w;
        } else {
            for (int e = e0; e < E; ++e) srcs[offsets[dst[e]] + ranks[e]] = src[e];
        }
        return;
    }
    __shared__ unsigned short smem[128 * QST];
    unsigned short* As = smem;
    unsigned short* Bs = smem + 4096;
    int q = blk - cb;
    int region = q % 3;
    int m0 = (q / 3) * 128;
    int wave = t >> 6, lane = t & 63;
    int wr = wave >> 1, wc = wave & 1;
    int lrow = lane & 15, kq = lane >> 4;
    int n0 = region * 128;
    int srow = t >> 2, scol8 = (t & 3) * 8;

    f32x4 acc[4][4] = {};
    for (int k0 = 0; k0 < 128; k0 += 32) {
        gload_lds16(A + (size_t)(m0 + srow) * 128 + k0 + scol8,      As + t * 8);
        gload_lds16(A + (size_t)(m0 + 64 + srow) * 128 + k0 + scol8, As + 2048 + t * 8);
        gload_lds16(Bt + (size_t)(n0 + srow) * 128 + k0 + scol8,      Bs + t * 8);
        gload_lds16(Bt + (size_t)(n0 + 64 + srow) * 128 + k0 + scol8, Bs + 2048 + t * 8);
        __syncthreads();
        bf16x8 af[4], bfr[4];
#pragma unroll
        for (int mi = 0; mi < 4; ++mi)
            af[mi] = *(const bf16x8*)(&As[(wr * 64 + mi * 16 + lrow) * 32 + kq * 8]);
#pragma unroll
        for (int ni = 0; ni < 4; ++ni)
            bfr[ni] = *(const bf16x8*)(&Bs[(wc * 64 + ni * 16 + lrow) * 32 + kq * 8]);
#pragma unroll
        for (int mi = 0; mi < 4; ++mi)
#pragma unroll
            for (int ni = 0; ni < 4; ++ni)
                acc[mi][ni] = __builtin_amdgcn_mfma_f32_16x16x32_bf16(af[mi], bfr[ni], acc[mi][ni], 0, 0, 0);
        __syncthreads();
    }

    float scale = (region == 0) ? QSCALE : 1.f;
#pragma unroll
    for (int ni = 0; ni < 4; ++ni) {
        int col = wc * 64 + ni * 16 + lrow;
#pragma unroll
        for (int mi = 0; mi < 4; ++mi) {
#pragma unroll
            for (int r = 0; r < 4; ++r) {
                int row = wr * 64 + mi * 16 + kq * 4 + r;
                smem[row * QST + col] = f2h(acc[mi][ni][r] * scale);
            }
        }
    }
    __syncthreads();
    if (region == 0) {
        unsigned short* outp = qb + (size_t)m0 * 128;
#pragma unroll
        for (int i = 0; i < 8; ++i) {
            int chunk = i * 256 + t;
            int row = chunk >> 4, c16 = chunk & 15;
            *(float4*)(outp + (size_t)chunk * 8) = *(const float4*)(smem + row * QST + c16 * 8);
        }
    } else {
        // fp8 convert + coalesced 16B stores: 128 rows x 8 chunks of 16 dims
        int half = region - 1;   // 0:k, 1:v
#pragma unroll
        for (int i = 0; i < 4; ++i) {
            int chunk = i * 256 + t;         // 0..1023
            int row = chunk >> 3, seg = chunk & 7;
            const unsigned short* sp = smem + row * QST + seg * 16;
            unsigned int ow[4];
#pragma unroll
            for (int j = 0; j < 4; ++j) {
                unsigned int lo = pk_fp8(h2f(sp[4 * j]), h2f(sp[4 * j + 1]));
                unsigned int hi = pk_fp8(h2f(sp[4 * j + 2]), h2f(sp[4 * j + 3]));
                ow[j] = lo | (hi << 16);
            }
            *(uint4*)(kv8 + (size_t)(m0 + row) * 256 + half * 128 + seg * 16) =
                make_uint4(ow[0], ow[1], ow[2], ow[3]);
        }
    }
}

// ---------------- k5: fused attention aggregate + residual + LN1 ----------------
// one wave per node; lane = (edge_slot e = lane>>3, head h = lane&7).
// srcs for iteration i+1 prefetched during iteration i: breaks the serial
// srcs-load -> kv-gather two-hop chain (kv gathers issue at loop top).
__global__ __launch_bounds__(256) void agg_ln1_kernel(
        const unsigned short* __restrict__ qb, const unsigned char* __restrict__ kv8,
        const float* __restrict__ feat,
        const int* __restrict__ srcs, const int* __restrict__ offsets,
        const float* __restrict__ g, const float* __restrict__ b,
        unsigned short* __restrict__ rstb, int n) {
    int node = blockIdx.x * 4 + (threadIdx.x >> 6);
    int lane = threadIdx.x & 63;
    if (node >= n) return;
    int el = lane >> 3;      // edge slot 0..7
    int h  = lane & 7;       // head 0..7

    // q for this head: 16 f16 (pre-scaled by QSCALE*log2e) -> 16 floats
    const uint4* qp = (const uint4*)(qb + (size_t)node * 128 + h * 16);
    uint4 qlo = qp[0], qhi = qp[1];
    float qf[16];
    {
        unsigned int qw[8] = {qlo.x, qlo.y, qlo.z, qlo.w, qhi.x, qhi.y, qhi.z, qhi.w};
#pragma unroll
        for (int j = 0; j < 8; ++j) {
            f16x2 p2 = __builtin_bit_cast(f16x2, qw[j]);
            qf[2 * j]     = (float)p2.x;
            qf[2 * j + 1] = (float)p2.y;
        }
    }

    int beg = offsets[node], end = offsets[node + 1];
    float l = 0.f;
    float acc[16];
#pragma unroll
    for (int j = 0; j < 16; ++j) acc[j] = 0.f;

    // prefetch first iteration's srcs
    int s0p = 0, s1p = 0;
    if (beg < end) {
        int e0i = beg + el, e1i = beg + 8 + el;
        s0p = srcs[(e0i < end) ? e0i : beg];
        s1p = srcs[(e1i < end) ? e1i : beg];
    }

    // 16 edges per iteration: 2 slots per lane; next iter's srcs prefetched early
    for (int idx = beg; idx < end; idx += 16) {
        int s0 = s0p, s1 = s1p;
        bool v0 = (idx + el) < end, v1 = (idx + 8 + el) < end;
        int nx = idx + 16;
        if (nx < end) {
            int e0i = nx + el, e1i = nx + 8 + el;
            s0p = srcs[(e0i < end) ? e0i : beg];
            s1p = srcs[(e1i < end) ? e1i : beg];
        }
        const uint4* kp0 = (const uint4*)(kv8 + (size_t)s0 * 256 + h * 16);
        const uint4* kp1 = (const uint4*)(kv8 + (size_t)s1 * 256 + h * 16);
        uint4 kw0 = kp0[0];
        uint4 vw0 = kp0[8];     // +128B
        uint4 kw1 = kp1[0];
        uint4 vw1 = kp1[8];

        float p0 = dot16_fp8(kw0, qf);
        float p1 = dot16_fp8(kw1, qf);
        float sc0 = v0 ? fminf(fmaxf(p0, -30.f), 30.f) : -1000.f;
        float sc1 = v1 ? fminf(fmaxf(p1, -30.f), 30.f) : -1000.f;
        float w0 = fexp2(sc0);
        float w1 = fexp2(sc1);
        l += w0 + w1;
        pv16_fp8(vw0, w0, acc);
        pv16_fp8(vw1, w1, acc);
    }

    // all-reduce softmax denom across the 8 edge-lanes (lane bits 3,4,5)
    l += __shfl_xor(l, 8, 64);
    l += __shfl_xor(l, 16, 64);
    l += __shfl_xor(l, 32, 64);

    // reduce-scatter acc over edge-lanes: each round halves dims, selects by e-bit
    float r8[8];
    {
        bool b0 = (el & 1) != 0;
#pragma unroll
        for (int j = 0; j < 8; ++j) {
            float send = b0 ? acc[j] : acc[j + 8];
            float keep = b0 ? acc[j + 8] : acc[j];
            r8[j] = keep + __shfl_xor(send, 8, 64);
        }
    }
    float r4[4];
    {
        bool b1 = (el & 2) != 0;
#pragma unroll
        for (int j = 0; j < 4; ++j) {
            float send = b1 ? r8[j] : r8[j + 4];
            float keep = b1 ? r8[j + 4] : r8[j];
            r4[j] = keep + __shfl_xor(send, 16, 64);
        }
    }
    float r2[2];
    {
        bool b2 = (el & 4) != 0;
#pragma unroll
        for (int j = 0; j < 2; ++j) {
            float send = b2 ? r4[j] : r4[j + 2];
            float keep = b2 ? r4[j + 2] : r4[j];
            r2[j] = keep + __shfl_xor(send, 32, 64);
        }
    }
    // lane now owns dims d0, d0+1 with d0 = h*16 + 8*e0 + 4*e1 + 2*e2
    int off = ((el & 1) << 3) | ((el & 2) << 1) | ((el & 4) >> 1);
    int d0 = h * 16 + off;

    float inv = (l > 0.f) ? 1.f / l : 0.f;
    float2 fv = *(const float2*)(feat + (size_t)node * DIM + d0);
    float x0 = r2[0] * inv + fv.x;
    float x1 = r2[1] * inv + fv.y;

    float s1 = x0 + x1;
    float s2 = x0 * x0 + x1 * x1;
#pragma unroll
    for (int off2 = 1; off2 < 64; off2 <<= 1) {
        s1 += __shfl_xor(s1, off2, 64);
        s2 += __shfl_xor(s2, off2, 64);
    }
    float mean = s1 * (1.f / DIM);
    float var = s2 * (1.f / DIM) - mean * mean;
    float rinv = rsqrtf(var + LN_EPS);
    float2 gv = *(const float2*)(g + d0);
    float2 bv = *(const float2*)(b + d0);
    float o0 = (x0 - mean) * rinv * gv.x + bv.x;
    float o1 = (x1 - mean) * rinv * gv.y + bv.y;
    unsigned int packed = (unsigned int)f2bf(o0) | ((unsigned int)f2bf(o1) << 16);
    ((unsigned int*)rstb)[(size_t)node * 64 + (d0 >> 1)] = packed;
}

// ---------------- k6: FFN1: hid = PReLU(rst @ W1 + b1), bf16 out ----------------
__global__ __launch_bounds__(256) void ffn1_gemm(
        const unsigned short* __restrict__ A, const unsigned short* __restrict__ Bt,
        unsigned short* __restrict__ hid,
        const float* __restrict__ b1, const float* __restrict__ prelu) {
    __shared__ unsigned short smem[128 * QST];
    unsigned short* As = smem;
    unsigned short* Bs = smem + 4096;
    int t = threadIdx.x;
    int wave = t >> 6, lane = t & 63;
    int wr = wave >> 1, wc = wave & 1;
    int lrow = lane & 15, kq = lane >> 4;
    int m0 = blockIdx.y * 128;
    int n0 = blockIdx.x * 128;
    int srow = t >> 2, scol8 = (t & 3) * 8;

    f32x4 acc[4][4] = {};
    for (int k0 = 0; k0 < 128; k0 += 32) {
        gload_lds16(A + (size_t)(m0 + srow) * 128 + k0 + scol8,      As + t * 8);
        gload_lds16(A + (size_t)(m0 + 64 + srow) * 128 + k0 + scol8, As + 2048 + t * 8);
        gload_lds16(Bt + (size_t)(n0 + srow) * 128 + k0 + scol8,      Bs + t * 8);
        gload_lds16(Bt + (size_t)(n0 + 64 + srow) * 128 + k0 + scol8, Bs + 2048 + t * 8);
        __syncthreads();
        bf16x8 af[4], bfr[4];
#pragma unroll
        for (int mi = 0; mi < 4; ++mi)
            af[mi] = *(const bf16x8*)(&As[(wr * 64 + mi * 16 + lrow) * 32 + kq * 8]);
#pragma unroll
        for (int ni = 0; ni < 4; ++ni)
            bfr[ni] = *(const bf16x8*)(&Bs[(wc * 64 + ni * 16 + lrow) * 32 + kq * 8]);
#pragma unroll
        for (int mi = 0; mi < 4; ++mi)
#pragma unroll
            for (int ni = 0; ni < 4; ++ni)
                acc[mi][ni] = __builtin_amdgcn_mfma_f32_16x16x32_bf16(af[mi], bfr[ni], acc[mi][ni], 0, 0, 0);
        __syncthreads();
    }

#pragma unroll
    for (int ni = 0; ni < 4; ++ni) {
        int col = wc * 64 + ni * 16 + lrow;
        int cg = n0 + col;
        float biv = b1[cg], pwv = prelu[cg];
#pragma unroll
        for (int mi = 0; mi < 4; ++mi) {
#pragma unroll
            for (int r = 0; r < 4; ++r) {
                int row = wr * 64 + mi * 16 + kq * 4 + r;
                float v = acc[mi][ni][r] + biv;
                v = v >= 0.f ? v : pwv * v;
                smem[row * QST + col] = f2bf(v);
            }
        }
    }
    __syncthreads();
#pragma unroll
    for (int i = 0; i < 8; ++i) {
        int chunk = i * 256 + t;
        int row = chunk >> 4, c16 = chunk & 15;
        *(float4*)(hid + (size_t)(m0 + row) * 512 + n0 + c16 * 8) =
            *(const float4*)(smem + row * QST + c16 * 8);
    }
}

// ---------------- k7: FFN2 + residual + LN2 ----------------
// grid (MP/64): 64-row tiles; wave w owns cols [w*32, w*32+32); two-phase LN reduction.
__global__ __launch_bounds__(256) void ffn2_ln2_kernel(
        const unsigned short* __restrict__ hid, const unsigned short* __restrict__ W2t,
        const unsigned short* __restrict__ rstb,
        const float* __restrict__ b2, const float* __restrict__ g, const float* __restrict__ bb,
        float* __restrict__ out, int Nn) {
    __shared__ unsigned short As[64 * 32];
    __shared__ unsigned short Bs[128 * 32];
    __shared__ float redS[64][4];
    __shared__ float redQ[64][4];
    int t = threadIdx.x;
    int wave = t >> 6, lane = t & 63;
    int lrow = lane & 15, kq = lane >> 4;
    int m0 = blockIdx.x * 64;
    int srow = t >> 2, scol8 = (t & 3) * 8;

    f32x4 acc[4][2] = {};
    for (int k0 = 0; k0 < 512; k0 += 32) {
        gload_lds16(hid + (size_t)(m0 + srow) * 512 + k0 + scol8, As + t * 8);
        gload_lds16(W2t + (size_t)srow * 512 + k0 + scol8,        Bs + t * 8);
        gload_lds16(W2t + (size_t)(64 + srow) * 512 + k0 + scol8, Bs + 2048 + t * 8);
        __syncthreads();
        bf16x8 af[4], bfr[2];
#pragma unroll
        for (int mi = 0; mi < 4; ++mi)
            af[mi] = *(const bf16x8*)(&As[(mi * 16 + lrow) * 32 + kq * 8]);
#pragma unroll
        for (int ni = 0; ni < 2; ++ni)
            bfr[ni] = *(const bf16x8*)(&Bs[(wave * 32 + ni * 16 + lrow) * 32 + kq * 8]);
#pragma unroll
        for (int mi = 0; mi < 4; ++mi)
#pragma unroll
            for (int ni = 0; ni < 2; ++ni)
                acc[mi][ni] = __builtin_amdgcn_mfma_f32_16x16x32_bf16(af[mi], bfr[ni], acc[mi][ni], 0, 0, 0);
        __syncthreads();
    }

    float b2v[2], gv[2], bv[2];
    int cols[2];
#pragma unroll
    for (int ni = 0; ni < 2; ++ni) {
        cols[ni] = wave * 32 + ni * 16 + lrow;
        b2v[ni] = b2[cols[ni]]; gv[ni] = g[cols[ni]]; bv[ni] = bb[cols[ni]];
    }
#pragma unroll
    for (int mi = 0; mi < 4; ++mi) {
#pragma unroll
        for (int r = 0; r < 4; ++r) {
            int rloc = mi * 16 + kq * 4 + r;
            int row = m0 + rloc;
            float ps = 0.f, pq = 0.f;
#pragma unroll
            for (int ni = 0; ni < 2; ++ni) {
                float rsv = bf2f(rstb[(size_t)row * 128 + cols[ni]]);
                float v = acc[mi][ni][r] + b2v[ni] + rsv;
                acc[mi][ni][r] = v;
                ps += v; pq += v * v;
            }
#pragma unroll
            for (int off = 1; off < 16; off <<= 1) {
                ps += __shfl_xor(ps, off, 16);
                pq += __shfl_xor(pq, off, 16);
            }
            if (lrow == 0) { redS[rloc][wave] = ps; redQ[rloc][wave] = pq; }
        }
    }
    __syncthreads();
#pragma unroll
    for (int mi = 0; mi < 4; ++mi) {
#pragma unroll
        for (int r = 0; r < 4; ++r) {
            int rloc = mi * 16 + kq * 4 + r;
            int row = m0 + rloc;
            float s1 = redS[rloc][0] + redS[rloc][1] + redS[rloc][2] + redS[rloc][3];
            float sq = redQ[rloc][0] + redQ[rloc][1] + redQ[rloc][2] + redQ[rloc][3];
            float mean = s1 * (1.f / DIM);
            float var = sq * (1.f / DIM) - mean * mean;
            float rs = rsqrtf(var + LN_EPS);
            if (row < Nn) {
#pragma unroll
                for (int ni = 0; ni < 2; ++ni)
                    out[(size_t)row * 128 + cols[ni]] =
                        (acc[mi][ni][r] - mean) * rs * gv[ni] + bv[ni];
            }
        }
    }
}

// ---------------- launch ----------------

extern "C" void kernel_launch(void* const* d_in, const int* in_sizes, int n_in,
                              void* d_out, int out_size, void* d_ws, size_t ws_size,
                              hipStream_t stream) {
    const float* feat   = (const float*)d_in[0];
    const int*   src    = (const int*)d_in[1];
    const int*   dst    = (const int*)d_in[2];
    const float* Wq     = (const float*)d_in[3];
    const float* Wk     = (const float*)d_in[4];
    const float* Wv     = (const float*)d_in[5];
    const float* ln1_g  = (const float*)d_in[6];
    const float* ln1_b  = (const float*)d_in[7];
    const float* ln2_g  = (const float*)d_in[8];
    const float* ln2_b  = (const float*)d_in[9];
    const float* W1     = (const float*)d_in[10];
    const float* b1     = (const float*)d_in[11];
    const float* prelu  = (const float*)d_in[12];
    const float* W2     = (const float*)d_in[13];
    const float* b2     = (const float*)d_in[14];
    float* out = (float*)d_out;

    const int Nn = in_sizes[0] / DIM;        // 40000
    const int E  = in_sizes[1];              // 640000
    const int MP = (Nn + 127) & ~127;        // 40064

    char* w = (char*)d_ws;
    unsigned short* qb   = (unsigned short*)w; w += (size_t)MP * DIM * 2;
    unsigned char*  kv8  = (unsigned char*)w;  w += (size_t)MP * 256;   // 128B k | 128B v per node
    unsigned short* rstb = (unsigned short*)w; w += (size_t)MP * DIM * 2;
    unsigned short* featb= (unsigned short*)w; w += (size_t)MP * DIM * 2;
    unsigned short* hid  = (unsigned short*)w; w += (size_t)MP * HID * 2;
    unsigned short* Wqkvt= (unsigned short*)w; w += 3 * DIM * DIM * 2;
    unsigned short* W1t  = (unsigned short*)w; w += (size_t)HID * DIM * 2;
    unsigned short* W2t  = (unsigned short*)w; w += (size_t)DIM * HID * 2;
    int* counts  = (int*)w;  w += (size_t)Nn * 4;
    int* offsets = (int*)w;  w += (size_t)(Nn + 4) * 4;
    int* bsum    = (int*)w;  w += 64 * 4;
    int* srcs    = (int*)w;
    // ranks aliases hid: hid written by ffn1 only AFTER fill_qkv consumed ranks
    int* ranks   = (int*)hid;

    const int NCH = (Nn + 1023) / 1024;      // 40 (<= 64)
    const int FB  = Nn / 8;                  // featb blocks (Nn*32 quads / 256)
    const int WB  = FB + 704;                // + weight transpose blocks
    const int CB  = (E + 1023) / 1024;       // count/fill blocks

    hipMemsetAsync(counts, 0, (size_t)Nn * 4, stream);

    prep_count_kernel<<<WB + CB, 256, 0, stream>>>(
        counts, ranks, Nn, feat, featb, Wq, Wk, Wv, Wqkvt, W1, W1t, W2, W2t, dst, E, FB, WB);

    scanA_kernel<<<NCH, 256, 0, stream>>>(counts, bsum, Nn);
    scanC_kernel<<<NCH, 256, 0, stream>>>(counts, bsum, offsets, Nn, NCH);

    fill_qkv_kernel<<<CB + 3 * (MP / 128), 256, 0, stream>>>(
        dst, src, ranks, offsets, srcs, E, CB, featb, Wqkvt, qb, kv8);

    agg_ln1_kernel<<<(Nn + 3) / 4, 256, 0, stream>>>(qb, kv8, feat,
                                                     srcs, offsets, ln1_g, ln1_b, rstb, Nn);

    {
        dim3 grid(4, MP / 128);
        ffn1_gemm<<<grid, 256, 0, stream>>>(rstb, W1t, hid, b1, prelu);
    }

    ffn2_ln2_kernel<<<MP / 64, 256, 0, stream>>>(hid, W2t, rstb, b2, ln2_g, ln2_b, out, Nn);
}